// Round 20
// baseline (214.463 us; speedup 1.0000x reference)
//
#include <hip/hip_runtime.h>
#include <math.h>

// FNO2d: B=4, C=3, H=W=256, L=4, WIDTH=32, M1=M2=12
// R20: R18 champion (211.1us) + the same confirmed footprint fix applied to
// k_dinvf: #pragma unroll 1 on phase A's mtl loop and the tail's kk loop
// (R18 proved rolled loops on gfx950 beat the unrolled ~25KB bodies: smaller
// live set -> no AGPR shuffle tax, I-cache-resident body).
//
// ws layout (u32/floats):
//   specA [8192 u32] : C2/65536 A-frags (hi 0..4095, lo 4096..)
//   tailA [8192 u32] : E A-frags  (hi, lo)
//   cwB   [4096 u32] : CW B-frags per layer (hi 0..2047, lo 2048..)
//   wB    [4096 u32] : MLP W0 B-frags (hi, lo)
//   w1p   [384 f32]  : W1 column-major [c][k]
//   h     [8388608]  : activations (B,32,H,W) fp32
//   tmp   [786432]   : ky-DFT out (B,32,H,12) complex; ALIASED with g
//   hfp   [294912]   : 4 x-partials of (B,32,24,12) complex

#define ANG0 0.024543692606170260f  // 2*pi/256

typedef __attribute__((ext_vector_type(8))) short bf16x8_t;
typedef __attribute__((ext_vector_type(4))) float f32x4_t;

__device__ __forceinline__ float fgelu(float v) {
    // exact-GELU via A&S 7.1.26 erf approx, |err| <= 1.5e-7, branchless
    float u = v * 0.70710678118f;
    float a = fabsf(u);
    float t = __builtin_amdgcn_rcpf(__builtin_fmaf(0.3275911f, a, 1.0f));
    float p = t * __builtin_fmaf(t, __builtin_fmaf(t, __builtin_fmaf(t,
                  __builtin_fmaf(t, 1.061405429f, -1.453152027f),
                  1.421413741f), -0.284496736f), 0.254829592f);
    float e = __expf(-u * u);
    float er = __builtin_fmaf(-p, e, 1.0f);
    er = copysignf(er, u);
    return 0.5f * v * (1.0f + er);
}

__device__ __forceinline__ unsigned packsplit(float v) {
    unsigned u = __float_as_uint(v);
    unsigned hi = u & 0xffff0000u;
    float r = v - __uint_as_float(hi);
    return hi | (__float_as_uint(r) >> 16);
}

__device__ __forceinline__ void fill_csp(float2* sCSP, int tid, int nthr) {
    for (int p = tid; p < 256; p += nthr)
        sCSP[p] = make_float2(cosf(p * ANG0), sinf(p * ANG0));
}

// ky-forward DFT (fp32, liftf only), pair-packed sVp layout.
__device__ __forceinline__ void ky_dft_tail(const float* sVp, const float2* sCSP,
                                            float* tmp, int b, int x, int y) {
    for (int idx = y; idx < 384; idx += 256) {
        int o = idx / 12, ky = idx % 12;
        const float* vp = sVp + o * 258;
        float vdc = vp[0], v128 = vp[256];
        float aR0 = vdc + ((ky & 1) ? -v128 : v128);
        float aR1 = 0.f, aI0 = 0.f, aI1 = 0.f;
#pragma unroll 4
        for (int yy = 1; yy <= 126; yy += 2) {
            int p0 = (ky * yy) & 255;
            int p1 = (p0 + ky) & 255;
            float2 c0 = sCSP[p0], c1 = sCSP[p1];
            float2 v0 = *reinterpret_cast<const float2*>(vp + 2 * yy);
            float2 v1 = *reinterpret_cast<const float2*>(vp + 2 * (yy + 1));
            aR0 = __builtin_fmaf(v0.x + v0.y, c0.x, aR0);
            aI0 = __builtin_fmaf(v0.x - v0.y, -c0.y, aI0);
            aR1 = __builtin_fmaf(v1.x + v1.y, c1.x, aR1);
            aI1 = __builtin_fmaf(v1.x - v1.y, -c1.y, aI1);
        }
        {
            int p = (ky * 127) & 255;
            float2 c = sCSP[p];
            float2 v0 = *reinterpret_cast<const float2*>(vp + 254);
            aR0 = __builtin_fmaf(v0.x + v0.y, c.x, aR0);
            aI0 = __builtin_fmaf(v0.x - v0.y, -c.y, aI0);
        }
        reinterpret_cast<float2*>(tmp + (((size_t)(b * 32 + o)) * 256 + x) * 24)[ky] =
            make_float2(aR0 + aR1, aI0 + aI1);
    }
}

__device__ __forceinline__ float c2val(int y, int j) {
    if (j >= 24 || j == 1) return 0.f;
    if (j == 0) return 1.f;
    int q = j >> 1;
    float ang = ((q * y) & 255) * ANG0;
    return (j & 1) ? -2.f * sinf(ang) : 2.f * cosf(ang);
}
__device__ __forceinline__ float etval(int j, int y) {
    if (j >= 24) return 0.f;
    int q = j >> 1;
    float ang = ((q * y) & 255) * ANG0;
    return (j & 1) ? -sinf(ang) : cosf(ang);
}
__device__ __forceinline__ void pack2(unsigned* dsthi, unsigned* dstlo,
                                      float v0, float v1) {
    unsigned u0 = __float_as_uint(v0), u1 = __float_as_uint(v1);
    *dsthi = ((u1 >> 16) << 16) | (u0 >> 16);
    float r0 = v0 - __uint_as_float(u0 & 0xffff0000u);
    float r1 = v1 - __uint_as_float(u1 & 0xffff0000u);
    *dstlo = ((__float_as_uint(r1) >> 16) << 16) | (__float_as_uint(r0) >> 16);
}

__global__ void k_init(const float* __restrict__ w0, const float* __restrict__ b0,
                       const float* __restrict__ w1, const float* __restrict__ cw,
                       unsigned* __restrict__ specA, unsigned* __restrict__ tailA,
                       unsigned* __restrict__ cwB, unsigned* __restrict__ wB,
                       float* __restrict__ w1p) {
    int t = threadIdx.x;
    const float SC = 1.0f / 65536.0f;
    for (int idx = t; idx < 4096; idx += 256) {   // specA: (C2/65536)[y][j]
        int w = idx & 3, lane = (idx >> 2) & 63, mt = idx >> 8;
        int y = mt * 16 + (lane & 15);
        int j0 = 8 * (lane >> 4) + 2 * w;
        pack2(&specA[idx], &specA[4096 + idx],
              c2val(y, j0) * SC, c2val(y, j0 + 1) * SC);
    }
    for (int idx = t; idx < 4096; idx += 256) {   // tailA: E[j][y] A-frags
        int w = idx & 3, lane = (idx >> 2) & 63, tt = idx >> 8;
        int kk = tt >> 1, mtj = tt & 1;
        int j = mtj * 16 + (lane & 15);
        int y0 = kk * 32 + 8 * (lane >> 4) + 2 * w;
        pack2(&tailA[idx], &tailA[4096 + idx], etval(j, y0), etval(j, y0 + 1));
    }
    for (int idx = t; idx < 2048; idx += 256) {   // cwB: CW[i][o] B-frags
        int w = idx & 3, lane = (idx >> 2) & 63, tt = idx >> 8;
        int l = tt >> 1, n = tt & 1;
        int o = n * 16 + (lane & 15);
        int i0 = 8 * (lane >> 4) + 2 * w;
        pack2(&cwB[idx], &cwB[2048 + idx],
              cw[l * 1024 + i0 * 32 + o], cw[l * 1024 + (i0 + 1) * 32 + o]);
    }
    for (int idx = t; idx < 2048; idx += 256) {   // wB: W0 B-frags
        int jw = idx & 3, lane = (idx >> 2) & 63, n = idx >> 8;
        int i0 = 8 * (lane >> 4) + 2 * jw;
        int km = n * 16 + (lane & 15);
        pack2(&wB[idx], &wB[2048 + idx], w0[i0 * 128 + km], w0[(i0 + 1) * 128 + km]);
    }
    for (int idx = t; idx < 384; idx += 256) {
        int c = idx >> 7, km = idx & 127;
        w1p[idx] = w1[km * 3 + c];
    }
}

// Lift + ky-forward DFT for layer 0 (fp32 h).
__global__ __launch_bounds__(256, 4) void k_liftf(const float* __restrict__ xin,
                                                  const float* __restrict__ pw,
                                                  const float* __restrict__ pb,
                                                  float* __restrict__ h,
                                                  float* __restrict__ tmp) {
    __shared__ float sVp[32 * 258];
    __shared__ float2 sCSP[256];
    int b = blockIdx.x >> 8, x = blockIdx.x & 255, y = threadIdx.x;
    fill_csp(sCSP, y, 256);
    int vslot = 2 * ((y <= 128) ? y : 256 - y) + ((y > 128) ? 1 : 0);
    float f0 = xin[((b * 3 + 0) * 256 + x) * 256 + y];
    float f1 = xin[((b * 3 + 1) * 256 + x) * 256 + y];
    float f2 = xin[((b * 3 + 2) * 256 + x) * 256 + y];
    float gx = x * (1.0f / 255.0f), gy = y * (1.0f / 255.0f);
#pragma unroll
    for (int o = 0; o < 32; ++o) {
        float v = pb[o] + f0 * pw[o] + f1 * pw[32 + o] + f2 * pw[64 + o]
                + gx * pw[96 + o] + gy * pw[128 + o];
        h[((b * 32 + o) * 256 + x) * 256 + y] = v;
        sVp[o * 258 + vslot] = v;
    }
    __syncthreads();
    ky_dft_tail(sVp, sCSP, tmp, b, x, y);
}

// kx-forward DFT (4-way x-split): hfp[part][plane][kxi][ky]
__global__ __launch_bounds__(320) void k_dftx(const float* __restrict__ tmp,
                                              float* __restrict__ hfp) {
    __shared__ float sT[1536];
    __shared__ float2 sCSP[256];
    int plane = blockIdx.x >> 2, part = blockIdx.x & 3;
    int x0 = part * 64;
    int tid = threadIdx.x;
    fill_csp(sCSP, tid, 320);
    for (int idx = tid; idx < 1536; idx += 320)
        sT[idx] = tmp[(size_t)plane * 6144 + x0 * 24 + idx];
    __syncthreads();
    if (tid < 288) {
        int kxi = tid / 12, ky = tid % 12;
        int kxv = kxi < 12 ? kxi : 232 + kxi;
        float aR = 0.f, aI = 0.f;
        for (int xp = 0; xp < 64; ++xp) {
            int p = (kxv * (x0 + xp)) & 255;
            float2 cs2 = sCSP[p];
            float tr = sT[xp * 24 + 2 * ky], ti = sT[xp * 24 + 2 * ky + 1];
            aR += tr * cs2.x + ti * cs2.y;
            aI += ti * cs2.x - tr * cs2.y;
        }
        hfp[(((size_t)part * 128 + plane) * 24 + kxi) * 24 + 2 * ky]     = aR;
        hfp[(((size_t)part * 128 + plane) * 24 + kxi) * 24 + 2 * ky + 1] = aI;
    }
}

// Mode mix + kx-inverse, one block per (b,o).
__global__ __launch_bounds__(320) void k_mixcinv(const float* __restrict__ hfp,
                                                 const float* __restrict__ w1r,
                                                 const float* __restrict__ w1i,
                                                 const float* __restrict__ w2r,
                                                 const float* __restrict__ w2i,
                                                 float* __restrict__ g, int l) {
    __shared__ float sA[576];
    __shared__ float2 sCSP[256];
    int b = blockIdx.x >> 5, o = blockIdx.x & 31;
    int tid = threadIdx.x;
    fill_csp(sCSP, tid, 320);
    if (tid < 288) {
        int kxi = tid / 12, ky = tid % 12;
        const float *wr, *wi;
        int rk;
        if (kxi < 12) { wr = w1r; wi = w1i; rk = kxi; }
        else          { wr = w2r; wi = w2i; rk = kxi - 12; }
        size_t wbase = ((size_t)l * 32 * 32) * 144 + (size_t)o * 144 + rk * 12 + ky;
        size_t hbase = (((size_t)(b * 32)) * 24 + kxi) * 24 + 2 * ky;
        float aR = 0.f, aI = 0.f;
#pragma unroll 4
        for (int i = 0; i < 32; ++i) {
            float2 h0 = *reinterpret_cast<const float2*>(hfp + hbase + i * 576);
            float2 h1 = *reinterpret_cast<const float2*>(hfp + 73728 + hbase + i * 576);
            float2 h2 = *reinterpret_cast<const float2*>(hfp + 147456 + hbase + i * 576);
            float2 h3 = *reinterpret_cast<const float2*>(hfp + 221184 + hbase + i * 576);
            float hr = h0.x + h1.x + h2.x + h3.x;
            float hi = h0.y + h1.y + h2.y + h3.y;
            float wrv = wr[wbase + (size_t)i * 4608];
            float wiv = wi[wbase + (size_t)i * 4608];
            aR += hr * wrv - hi * wiv;
            aI += hr * wiv + hi * wrv;
        }
        sA[kxi * 24 + 2 * ky]     = aR;
        sA[kxi * 24 + 2 * ky + 1] = aI;
    }
    __syncthreads();
    if (tid < 256) {
        int x = tid;
        float out[24];
#pragma unroll
        for (int j = 0; j < 24; ++j) out[j] = 0.f;
        for (int kxi = 0; kxi < 24; ++kxi) {
            int kxv = kxi < 12 ? kxi : 232 + kxi;
            int p = (kxv * x) & 255;
            float2 cs2 = sCSP[p];
#pragma unroll
            for (int ky = 0; ky < 12; ++ky) {
                float ar = sA[kxi * 24 + 2 * ky], ai = sA[kxi * 24 + 2 * ky + 1];
                out[2 * ky]     += ar * cs2.x - ai * cs2.y;
                out[2 * ky + 1] += ar * cs2.y + ai * cs2.x;
            }
        }
        float* gp = g + ((size_t)(b * 32 + o)) * 6144 + x * 24;
#pragma unroll
        for (int j = 0; j < 24; ++j) gp[j] = out[j];
    }
}

// Shared phase A: spec+bypass GEMMs into packed sVvT. ACT: apply gelu.
// mtl loop ROLLED (R18-confirmed footprint fix).
template <int ACT>
__device__ __forceinline__ void dinv_phaseA(const float* __restrict__ h,
                                            const float* __restrict__ g,
                                            const unsigned* __restrict__ specA,
                                            const unsigned* __restrict__ cwB,
                                            const float* __restrict__ cb,
                                            unsigned* sVvT, int b, int x, int l,
                                            int wv, int lane) {
    int l15 = lane & 15, l4 = lane >> 4;
    // G B-fragments (both n-tiles), raw g (specA carries the 1/65536).
    bf16x8_t Ghi[2], Glo[2];
#pragma unroll
    for (int n = 0; n < 2; ++n) {
        float gv[8];
        if (l4 < 3) {
            const float* gp = g + (size_t)(b * 32 + n * 16 + l15) * 6144
                            + x * 24 + 8 * l4;
            float4 a = *reinterpret_cast<const float4*>(gp);
            float4 c = *reinterpret_cast<const float4*>(gp + 4);
            gv[0] = a.x; gv[1] = a.y; gv[2] = a.z; gv[3] = a.w;
            gv[4] = c.x; gv[5] = c.y; gv[6] = c.z; gv[7] = c.w;
        } else {
#pragma unroll
            for (int j = 0; j < 8; ++j) gv[j] = 0.f;
        }
#pragma unroll
        for (int j = 0; j < 8; ++j) {
            float v = gv[j];
            unsigned u = __float_as_uint(v);
            Ghi[n][j] = (short)(u >> 16);
            float r = v - __uint_as_float(u & 0xffff0000u);
            Glo[n][j] = (short)(__float_as_uint(r) >> 16);
        }
    }
    bf16x8_t Whi[2], Wlo[2];
#pragma unroll
    for (int n = 0; n < 2; ++n) {
        Whi[n] = *reinterpret_cast<const bf16x8_t*>(cwB + ((l * 2 + n) * 64 + lane) * 4);
        Wlo[n] = *reinterpret_cast<const bf16x8_t*>(cwB + 2048 + ((l * 2 + n) * 64 + lane) * 4);
    }
    float cbb[2] = {cb[l * 32 + l15], cb[l * 32 + 16 + l15]};
#pragma unroll 1
    for (int mtl = 0; mtl < 4; ++mtl) {
        int mtg = wv * 4 + mtl;
        bf16x8_t C2hi = *reinterpret_cast<const bf16x8_t*>(specA + (mtg * 64 + lane) * 4);
        bf16x8_t C2lo = *reinterpret_cast<const bf16x8_t*>(specA + 4096 + (mtg * 64 + lane) * 4);
        bf16x8_t Hhi, Hlo;
        {
            const float* hp = h + (size_t)(b * 32) * 65536 + x * 256 + mtg * 16 + l15;
#pragma unroll
            for (int j = 0; j < 8; ++j) {
                float v = hp[(size_t)(8 * l4 + j) * 65536];
                unsigned u = __float_as_uint(v);
                Hhi[j] = (short)(u >> 16);
                float r = v - __uint_as_float(u & 0xffff0000u);
                Hlo[j] = (short)(__float_as_uint(r) >> 16);
            }
        }
#pragma unroll
        for (int n = 0; n < 2; ++n) {
            f32x4_t acc = {0.f, 0.f, 0.f, 0.f};
            acc = __builtin_amdgcn_mfma_f32_16x16x32_bf16(C2hi, Ghi[n], acc, 0, 0, 0);
            acc = __builtin_amdgcn_mfma_f32_16x16x32_bf16(C2lo, Ghi[n], acc, 0, 0, 0);
            acc = __builtin_amdgcn_mfma_f32_16x16x32_bf16(C2hi, Glo[n], acc, 0, 0, 0);
            acc = __builtin_amdgcn_mfma_f32_16x16x32_bf16(Hhi, Whi[n], acc, 0, 0, 0);
            acc = __builtin_amdgcn_mfma_f32_16x16x32_bf16(Hlo, Whi[n], acc, 0, 0, 0);
            acc = __builtin_amdgcn_mfma_f32_16x16x32_bf16(Hhi, Wlo[n], acc, 0, 0, 0);
            uint4 pu;
            {
                float v0 = acc[0] + cbb[n], v1 = acc[1] + cbb[n];
                float v2 = acc[2] + cbb[n], v3 = acc[3] + cbb[n];
                if (ACT) { v0 = fgelu(v0); v1 = fgelu(v1); v2 = fgelu(v2); v3 = fgelu(v3); }
                pu.x = packsplit(v0); pu.y = packsplit(v1);
                pu.z = packsplit(v2); pu.w = packsplit(v3);
            }
            *reinterpret_cast<uint4*>(&sVvT[(n * 16 + l15) * 260 + mtg * 16 + l4 * 4]) = pu;
        }
    }
}

// Layers 0..2: MFMA spec+bypass+gelu, h write, MFMA ky-DFT tail (kk rolled).
__global__ __launch_bounds__(256) void k_dinvf(float* __restrict__ h,
                                               const float* __restrict__ g,
                                               const unsigned* __restrict__ specA,
                                               const unsigned* __restrict__ tailA,
                                               const unsigned* __restrict__ cwB,
                                               const float* __restrict__ cb,
                                               float* __restrict__ tmp, int l) {
    __shared__ unsigned sVvT[32 * 260];
    int b = blockIdx.x >> 8, x = blockIdx.x & 255;
    int tid = threadIdx.x, wv = tid >> 6, lane = tid & 63;
    int l15 = lane & 15, l4 = lane >> 4;
    dinv_phaseA<1>(h, g, specA, cwB, cb, sVvT, b, x, l, wv, lane);
    __syncthreads();
    // h write (coalesced): reconstruct fp32 = bf(hi) + bf(lo).
    {
        size_t hb = (size_t)(b * 32) * 65536 + x * 256 + tid;
#pragma unroll 8
        for (int o = 0; o < 32; ++o) {
            unsigned u = sVvT[o * 260 + tid];
            h[hb + (size_t)o * 65536] =
                __uint_as_float(u & 0xffff0000u) + __uint_as_float(u << 16);
        }
    }
    // tail GEMM: wave quadrant (mtj, nq), kk loop rolled.
    {
        int mtj = wv >> 1, nq = wv & 1;
        f32x4_t acc = {0.f, 0.f, 0.f, 0.f};
#pragma unroll 1
        for (int kk = 0; kk < 8; ++kk) {
            bf16x8_t Ehi = *reinterpret_cast<const bf16x8_t*>(
                tailA + ((kk * 2 + mtj) * 64 + lane) * 4);
            bf16x8_t Elo = *reinterpret_cast<const bf16x8_t*>(
                tailA + 4096 + ((kk * 2 + mtj) * 64 + lane) * 4);
            int base = (nq * 16 + l15) * 260 + kk * 32 + 8 * l4;
            uint4 va = *reinterpret_cast<const uint4*>(&sVvT[base]);
            uint4 vb = *reinterpret_cast<const uint4*>(&sVvT[base + 4]);
            bf16x8_t Vhi, Vlo;
            Vhi[0] = (short)(va.x >> 16); Vlo[0] = (short)(va.x & 0xffffu);
            Vhi[1] = (short)(va.y >> 16); Vlo[1] = (short)(va.y & 0xffffu);
            Vhi[2] = (short)(va.z >> 16); Vlo[2] = (short)(va.z & 0xffffu);
            Vhi[3] = (short)(va.w >> 16); Vlo[3] = (short)(va.w & 0xffffu);
            Vhi[4] = (short)(vb.x >> 16); Vlo[4] = (short)(vb.x & 0xffffu);
            Vhi[5] = (short)(vb.y >> 16); Vlo[5] = (short)(vb.y & 0xffffu);
            Vhi[6] = (short)(vb.z >> 16); Vlo[6] = (short)(vb.z & 0xffffu);
            Vhi[7] = (short)(vb.w >> 16); Vlo[7] = (short)(vb.w & 0xffffu);
            acc = __builtin_amdgcn_mfma_f32_16x16x32_bf16(Ehi, Vhi, acc, 0, 0, 0);
            acc = __builtin_amdgcn_mfma_f32_16x16x32_bf16(Ehi, Vlo, acc, 0, 0, 0);
            acc = __builtin_amdgcn_mfma_f32_16x16x32_bf16(Elo, Vhi, acc, 0, 0, 0);
        }
        int j0 = mtj * 16 + l4 * 4;
        if (j0 < 24) {
            float4 st = {acc[0], acc[1], acc[2], acc[3]};
            *reinterpret_cast<float4*>(
                tmp + (size_t)(b * 32 + nq * 16 + l15) * 6144 + x * 24 + j0) = st;
        }
    }
}

// Layer 3 (no gelu) + final MLP; phase B mt-tile-at-a-time (rolled loops).
__global__ __launch_bounds__(256) void k_dinvmlp(const float* __restrict__ h,
                                                 const float* __restrict__ g,
                                                 const unsigned* __restrict__ specA,
                                                 const unsigned* __restrict__ cwB,
                                                 const float* __restrict__ cb,
                                                 const unsigned* __restrict__ wB,
                                                 const float* __restrict__ b0,
                                                 const float* __restrict__ w1p,
                                                 const float* __restrict__ b1,
                                                 float* __restrict__ out) {
    __shared__ unsigned sVvT[32 * 260];
    __shared__ float sOut[256 * 5];
    int b = blockIdx.x >> 8, x = blockIdx.x & 255;
    int tid = threadIdx.x, wv = tid >> 6, lane = tid & 63;
    int l15 = lane & 15, l4 = lane >> 4;
    dinv_phaseA<0>(h, g, specA, cwB, cb, sVvT, b, x, 3, wv, lane);
    __syncthreads();
    // Phase B: per mt-tile: A-frags, n-loop (3 MFMA + gelu + W1 fma), reduce.
#pragma unroll 1
    for (int mt = 0; mt < 4; ++mt) {
        bf16x8_t Ahi, Alo;
        int rowY = (wv << 6) + (mt << 4) + l15;
#pragma unroll
        for (int j = 0; j < 8; ++j) {
            unsigned u = sVvT[(8 * l4 + j) * 260 + rowY];
            Ahi[j] = (short)(u >> 16);
            Alo[j] = (short)(u & 0xffffu);
        }
        float ap0[4], ap1[4], ap2[4];
#pragma unroll
        for (int r = 0; r < 4; ++r) { ap0[r] = 0.f; ap1[r] = 0.f; ap2[r] = 0.f; }
#pragma unroll 1
        for (int n = 0; n < 8; ++n) {
            bf16x8_t Bhi = *reinterpret_cast<const bf16x8_t*>(wB + (n * 64 + lane) * 4);
            bf16x8_t Blo = *reinterpret_cast<const bf16x8_t*>(wB + 2048 + (n * 64 + lane) * 4);
            int km = (n << 4) + l15;
            float b0v  = b0[km];
            float w1v0 = w1p[km], w1v1 = w1p[128 + km], w1v2 = w1p[256 + km];
            f32x4_t acc = {0.f, 0.f, 0.f, 0.f};
            acc = __builtin_amdgcn_mfma_f32_16x16x32_bf16(Ahi, Bhi, acc, 0, 0, 0);
            acc = __builtin_amdgcn_mfma_f32_16x16x32_bf16(Ahi, Blo, acc, 0, 0, 0);
            acc = __builtin_amdgcn_mfma_f32_16x16x32_bf16(Alo, Bhi, acc, 0, 0, 0);
#pragma unroll
            for (int r = 0; r < 4; ++r) {
                float tg = fgelu(acc[r] + b0v);
                ap0[r] = __builtin_fmaf(tg, w1v0, ap0[r]);
                ap1[r] = __builtin_fmaf(tg, w1v1, ap1[r]);
                ap2[r] = __builtin_fmaf(tg, w1v2, ap2[r]);
            }
        }
#pragma unroll
        for (int r = 0; r < 4; ++r) {
            float v0 = ap0[r], v1 = ap1[r], v2 = ap2[r];
            v0 += __shfl_xor(v0, 1); v1 += __shfl_xor(v1, 1); v2 += __shfl_xor(v2, 1);
            v0 += __shfl_xor(v0, 2); v1 += __shfl_xor(v1, 2); v2 += __shfl_xor(v2, 2);
            v0 += __shfl_xor(v0, 4); v1 += __shfl_xor(v1, 4); v2 += __shfl_xor(v2, 4);
            v0 += __shfl_xor(v0, 8); v1 += __shfl_xor(v1, 8); v2 += __shfl_xor(v2, 8);
            if (l15 == 0) {
                int row = (wv << 6) + (mt << 4) + (l4 << 2) + r;
                sOut[row * 5 + 0] = v0;
                sOut[row * 5 + 1] = v1;
                sOut[row * 5 + 2] = v2;
            }
        }
    }
    __syncthreads();
    float b1v0 = b1[0], b1v1 = b1[1], b1v2 = b1[2];
    out[(((size_t)b * 3 + 0) * 256 + x) * 256 + tid] = sOut[tid * 5 + 0] + b1v0;
    out[(((size_t)b * 3 + 1) * 256 + x) * 256 + tid] = sOut[tid * 5 + 1] + b1v1;
    out[(((size_t)b * 3 + 2) * 256 + x) * 256 + tid] = sOut[tid * 5 + 2] + b1v2;
}

extern "C" void kernel_launch(void* const* d_in, const int* in_sizes, int n_in,
                              void* d_out, int out_size, void* d_ws, size_t ws_size,
                              hipStream_t stream) {
    const float* xin  = (const float*)d_in[0];
    const float* pw   = (const float*)d_in[1];
    const float* pb   = (const float*)d_in[2];
    const float* sw1r = (const float*)d_in[3];
    const float* sw1i = (const float*)d_in[4];
    const float* sw2r = (const float*)d_in[5];
    const float* sw2i = (const float*)d_in[6];
    const float* cw   = (const float*)d_in[7];
    const float* cb   = (const float*)d_in[8];
    const float* w0   = (const float*)d_in[9];
    const float* b0   = (const float*)d_in[10];
    const float* w1   = (const float*)d_in[11];
    const float* b1   = (const float*)d_in[12];
    float* out = (float*)d_out;

    unsigned* specA = (unsigned*)d_ws;         // 8192 u32
    unsigned* tailA = specA + 8192;            // 8192
    unsigned* cwB   = tailA + 8192;            // 4096
    unsigned* wB    = cwB + 4096;              // 4096
    float* w1p = (float*)(wB + 4096);          // 384
    float* h   = w1p + 384;                    // 8388608
    float* tmp = h + 8388608;                  // 786432 (aliased with g)
    float* hfp = tmp + 786432;                 // 294912
    float* g   = tmp;                          // alias

    k_init<<<1, 256, 0, stream>>>(w0, b0, w1, cw, specA, tailA, cwB, wB, w1p);
    k_liftf<<<1024, 256, 0, stream>>>(xin, pw, pb, h, tmp);
    for (int l = 0; l < 4; ++l) {
        k_dftx<<<512, 320, 0, stream>>>(tmp, hfp);
        k_mixcinv<<<128, 320, 0, stream>>>(hfp, sw1r, sw1i, sw2r, sw2i, g, l);
        if (l < 3)
            k_dinvf<<<1024, 256, 0, stream>>>(h, g, specA, tailA, cwB, cb, tmp, l);
        else
            k_dinvmlp<<<1024, 256, 0, stream>>>(h, g, specA, cwB, cb, wB, b0, w1p,
                                                b1, out);
    }
}

// Round 21
// 210.609 us; speedup vs baseline: 1.0183x; 1.0183x over previous
//
#include <hip/hip_runtime.h>
#include <math.h>

// FNO2d: B=4, C=3, H=W=256, L=4, WIDTH=32, M1=M2=12
// R21: clean revert to the R18 champion (211.1us) — R19's rolled-loop
// variants of dinvf phase A / tail were a ~3us regression (the footprint fix
// that saved dinvmlp phase B did not transfer; phase A's live set is bounded
// by loop-invariant fragments). This is the best-measured configuration:
// full-MFMA dinv layers, fp32 h, fused dinvmlp with mt-tile-rolled phase B.
//
// ws layout (u32/floats):
//   specA [8192 u32] : C2/65536 A-frags (hi 0..4095, lo 4096..)
//   tailA [8192 u32] : E A-frags  (hi, lo)
//   cwB   [4096 u32] : CW B-frags per layer (hi 0..2047, lo 2048..)
//   wB    [4096 u32] : MLP W0 B-frags (hi, lo)
//   w1p   [384 f32]  : W1 column-major [c][k]
//   h     [8388608]  : activations (B,32,H,W) fp32
//   tmp   [786432]   : ky-DFT out (B,32,H,12) complex; ALIASED with g
//   hfp   [294912]   : 4 x-partials of (B,32,24,12) complex

#define ANG0 0.024543692606170260f  // 2*pi/256

typedef __attribute__((ext_vector_type(8))) short bf16x8_t;
typedef __attribute__((ext_vector_type(4))) float f32x4_t;

__device__ __forceinline__ float fgelu(float v) {
    // exact-GELU via A&S 7.1.26 erf approx, |err| <= 1.5e-7, branchless
    float u = v * 0.70710678118f;
    float a = fabsf(u);
    float t = __builtin_amdgcn_rcpf(__builtin_fmaf(0.3275911f, a, 1.0f));
    float p = t * __builtin_fmaf(t, __builtin_fmaf(t, __builtin_fmaf(t,
                  __builtin_fmaf(t, 1.061405429f, -1.453152027f),
                  1.421413741f), -0.284496736f), 0.254829592f);
    float e = __expf(-u * u);
    float er = __builtin_fmaf(-p, e, 1.0f);
    er = copysignf(er, u);
    return 0.5f * v * (1.0f + er);
}

__device__ __forceinline__ unsigned packsplit(float v) {
    unsigned u = __float_as_uint(v);
    unsigned hi = u & 0xffff0000u;
    float r = v - __uint_as_float(hi);
    return hi | (__float_as_uint(r) >> 16);
}

__device__ __forceinline__ void fill_csp(float2* sCSP, int tid, int nthr) {
    for (int p = tid; p < 256; p += nthr)
        sCSP[p] = make_float2(cosf(p * ANG0), sinf(p * ANG0));
}

// ky-forward DFT (fp32, liftf only), pair-packed sVp layout.
__device__ __forceinline__ void ky_dft_tail(const float* sVp, const float2* sCSP,
                                            float* tmp, int b, int x, int y) {
    for (int idx = y; idx < 384; idx += 256) {
        int o = idx / 12, ky = idx % 12;
        const float* vp = sVp + o * 258;
        float vdc = vp[0], v128 = vp[256];
        float aR0 = vdc + ((ky & 1) ? -v128 : v128);
        float aR1 = 0.f, aI0 = 0.f, aI1 = 0.f;
#pragma unroll 4
        for (int yy = 1; yy <= 126; yy += 2) {
            int p0 = (ky * yy) & 255;
            int p1 = (p0 + ky) & 255;
            float2 c0 = sCSP[p0], c1 = sCSP[p1];
            float2 v0 = *reinterpret_cast<const float2*>(vp + 2 * yy);
            float2 v1 = *reinterpret_cast<const float2*>(vp + 2 * (yy + 1));
            aR0 = __builtin_fmaf(v0.x + v0.y, c0.x, aR0);
            aI0 = __builtin_fmaf(v0.x - v0.y, -c0.y, aI0);
            aR1 = __builtin_fmaf(v1.x + v1.y, c1.x, aR1);
            aI1 = __builtin_fmaf(v1.x - v1.y, -c1.y, aI1);
        }
        {
            int p = (ky * 127) & 255;
            float2 c = sCSP[p];
            float2 v0 = *reinterpret_cast<const float2*>(vp + 254);
            aR0 = __builtin_fmaf(v0.x + v0.y, c.x, aR0);
            aI0 = __builtin_fmaf(v0.x - v0.y, -c.y, aI0);
        }
        reinterpret_cast<float2*>(tmp + (((size_t)(b * 32 + o)) * 256 + x) * 24)[ky] =
            make_float2(aR0 + aR1, aI0 + aI1);
    }
}

__device__ __forceinline__ float c2val(int y, int j) {
    if (j >= 24 || j == 1) return 0.f;
    if (j == 0) return 1.f;
    int q = j >> 1;
    float ang = ((q * y) & 255) * ANG0;
    return (j & 1) ? -2.f * sinf(ang) : 2.f * cosf(ang);
}
__device__ __forceinline__ float etval(int j, int y) {
    if (j >= 24) return 0.f;
    int q = j >> 1;
    float ang = ((q * y) & 255) * ANG0;
    return (j & 1) ? -sinf(ang) : cosf(ang);
}
__device__ __forceinline__ void pack2(unsigned* dsthi, unsigned* dstlo,
                                      float v0, float v1) {
    unsigned u0 = __float_as_uint(v0), u1 = __float_as_uint(v1);
    *dsthi = ((u1 >> 16) << 16) | (u0 >> 16);
    float r0 = v0 - __uint_as_float(u0 & 0xffff0000u);
    float r1 = v1 - __uint_as_float(u1 & 0xffff0000u);
    *dstlo = ((__float_as_uint(r1) >> 16) << 16) | (__float_as_uint(r0) >> 16);
}

__global__ void k_init(const float* __restrict__ w0, const float* __restrict__ b0,
                       const float* __restrict__ w1, const float* __restrict__ cw,
                       unsigned* __restrict__ specA, unsigned* __restrict__ tailA,
                       unsigned* __restrict__ cwB, unsigned* __restrict__ wB,
                       float* __restrict__ w1p) {
    int t = threadIdx.x;
    const float SC = 1.0f / 65536.0f;
    for (int idx = t; idx < 4096; idx += 256) {   // specA: (C2/65536)[y][j]
        int w = idx & 3, lane = (idx >> 2) & 63, mt = idx >> 8;
        int y = mt * 16 + (lane & 15);
        int j0 = 8 * (lane >> 4) + 2 * w;
        pack2(&specA[idx], &specA[4096 + idx],
              c2val(y, j0) * SC, c2val(y, j0 + 1) * SC);
    }
    for (int idx = t; idx < 4096; idx += 256) {   // tailA: E[j][y] A-frags
        int w = idx & 3, lane = (idx >> 2) & 63, tt = idx >> 8;
        int kk = tt >> 1, mtj = tt & 1;
        int j = mtj * 16 + (lane & 15);
        int y0 = kk * 32 + 8 * (lane >> 4) + 2 * w;
        pack2(&tailA[idx], &tailA[4096 + idx], etval(j, y0), etval(j, y0 + 1));
    }
    for (int idx = t; idx < 2048; idx += 256) {   // cwB: CW[i][o] B-frags
        int w = idx & 3, lane = (idx >> 2) & 63, tt = idx >> 8;
        int l = tt >> 1, n = tt & 1;
        int o = n * 16 + (lane & 15);
        int i0 = 8 * (lane >> 4) + 2 * w;
        pack2(&cwB[idx], &cwB[2048 + idx],
              cw[l * 1024 + i0 * 32 + o], cw[l * 1024 + (i0 + 1) * 32 + o]);
    }
    for (int idx = t; idx < 2048; idx += 256) {   // wB: W0 B-frags
        int jw = idx & 3, lane = (idx >> 2) & 63, n = idx >> 8;
        int i0 = 8 * (lane >> 4) + 2 * jw;
        int km = n * 16 + (lane & 15);
        pack2(&wB[idx], &wB[2048 + idx], w0[i0 * 128 + km], w0[(i0 + 1) * 128 + km]);
    }
    for (int idx = t; idx < 384; idx += 256) {
        int c = idx >> 7, km = idx & 127;
        w1p[idx] = w1[km * 3 + c];
    }
}

// Lift + ky-forward DFT for layer 0 (fp32 h).
__global__ __launch_bounds__(256, 4) void k_liftf(const float* __restrict__ xin,
                                                  const float* __restrict__ pw,
                                                  const float* __restrict__ pb,
                                                  float* __restrict__ h,
                                                  float* __restrict__ tmp) {
    __shared__ float sVp[32 * 258];
    __shared__ float2 sCSP[256];
    int b = blockIdx.x >> 8, x = blockIdx.x & 255, y = threadIdx.x;
    fill_csp(sCSP, y, 256);
    int vslot = 2 * ((y <= 128) ? y : 256 - y) + ((y > 128) ? 1 : 0);
    float f0 = xin[((b * 3 + 0) * 256 + x) * 256 + y];
    float f1 = xin[((b * 3 + 1) * 256 + x) * 256 + y];
    float f2 = xin[((b * 3 + 2) * 256 + x) * 256 + y];
    float gx = x * (1.0f / 255.0f), gy = y * (1.0f / 255.0f);
#pragma unroll
    for (int o = 0; o < 32; ++o) {
        float v = pb[o] + f0 * pw[o] + f1 * pw[32 + o] + f2 * pw[64 + o]
                + gx * pw[96 + o] + gy * pw[128 + o];
        h[((b * 32 + o) * 256 + x) * 256 + y] = v;
        sVp[o * 258 + vslot] = v;
    }
    __syncthreads();
    ky_dft_tail(sVp, sCSP, tmp, b, x, y);
}

// kx-forward DFT (4-way x-split): hfp[part][plane][kxi][ky]
__global__ __launch_bounds__(320) void k_dftx(const float* __restrict__ tmp,
                                              float* __restrict__ hfp) {
    __shared__ float sT[1536];
    __shared__ float2 sCSP[256];
    int plane = blockIdx.x >> 2, part = blockIdx.x & 3;
    int x0 = part * 64;
    int tid = threadIdx.x;
    fill_csp(sCSP, tid, 320);
    for (int idx = tid; idx < 1536; idx += 320)
        sT[idx] = tmp[(size_t)plane * 6144 + x0 * 24 + idx];
    __syncthreads();
    if (tid < 288) {
        int kxi = tid / 12, ky = tid % 12;
        int kxv = kxi < 12 ? kxi : 232 + kxi;
        float aR = 0.f, aI = 0.f;
        for (int xp = 0; xp < 64; ++xp) {
            int p = (kxv * (x0 + xp)) & 255;
            float2 cs2 = sCSP[p];
            float tr = sT[xp * 24 + 2 * ky], ti = sT[xp * 24 + 2 * ky + 1];
            aR += tr * cs2.x + ti * cs2.y;
            aI += ti * cs2.x - tr * cs2.y;
        }
        hfp[(((size_t)part * 128 + plane) * 24 + kxi) * 24 + 2 * ky]     = aR;
        hfp[(((size_t)part * 128 + plane) * 24 + kxi) * 24 + 2 * ky + 1] = aI;
    }
}

// Mode mix + kx-inverse, one block per (b,o).
__global__ __launch_bounds__(320) void k_mixcinv(const float* __restrict__ hfp,
                                                 const float* __restrict__ w1r,
                                                 const float* __restrict__ w1i,
                                                 const float* __restrict__ w2r,
                                                 const float* __restrict__ w2i,
                                                 float* __restrict__ g, int l) {
    __shared__ float sA[576];
    __shared__ float2 sCSP[256];
    int b = blockIdx.x >> 5, o = blockIdx.x & 31;
    int tid = threadIdx.x;
    fill_csp(sCSP, tid, 320);
    if (tid < 288) {
        int kxi = tid / 12, ky = tid % 12;
        const float *wr, *wi;
        int rk;
        if (kxi < 12) { wr = w1r; wi = w1i; rk = kxi; }
        else          { wr = w2r; wi = w2i; rk = kxi - 12; }
        size_t wbase = ((size_t)l * 32 * 32) * 144 + (size_t)o * 144 + rk * 12 + ky;
        size_t hbase = (((size_t)(b * 32)) * 24 + kxi) * 24 + 2 * ky;
        float aR = 0.f, aI = 0.f;
#pragma unroll 4
        for (int i = 0; i < 32; ++i) {
            float2 h0 = *reinterpret_cast<const float2*>(hfp + hbase + i * 576);
            float2 h1 = *reinterpret_cast<const float2*>(hfp + 73728 + hbase + i * 576);
            float2 h2 = *reinterpret_cast<const float2*>(hfp + 147456 + hbase + i * 576);
            float2 h3 = *reinterpret_cast<const float2*>(hfp + 221184 + hbase + i * 576);
            float hr = h0.x + h1.x + h2.x + h3.x;
            float hi = h0.y + h1.y + h2.y + h3.y;
            float wrv = wr[wbase + (size_t)i * 4608];
            float wiv = wi[wbase + (size_t)i * 4608];
            aR += hr * wrv - hi * wiv;
            aI += hr * wiv + hi * wrv;
        }
        sA[kxi * 24 + 2 * ky]     = aR;
        sA[kxi * 24 + 2 * ky + 1] = aI;
    }
    __syncthreads();
    if (tid < 256) {
        int x = tid;
        float out[24];
#pragma unroll
        for (int j = 0; j < 24; ++j) out[j] = 0.f;
        for (int kxi = 0; kxi < 24; ++kxi) {
            int kxv = kxi < 12 ? kxi : 232 + kxi;
            int p = (kxv * x) & 255;
            float2 cs2 = sCSP[p];
#pragma unroll
            for (int ky = 0; ky < 12; ++ky) {
                float ar = sA[kxi * 24 + 2 * ky], ai = sA[kxi * 24 + 2 * ky + 1];
                out[2 * ky]     += ar * cs2.x - ai * cs2.y;
                out[2 * ky + 1] += ar * cs2.y + ai * cs2.x;
            }
        }
        float* gp = g + ((size_t)(b * 32 + o)) * 6144 + x * 24;
#pragma unroll
        for (int j = 0; j < 24; ++j) gp[j] = out[j];
    }
}

// Shared phase A: spec+bypass GEMMs into packed sVvT. ACT: apply gelu.
template <int ACT>
__device__ __forceinline__ void dinv_phaseA(const float* __restrict__ h,
                                            const float* __restrict__ g,
                                            const unsigned* __restrict__ specA,
                                            const unsigned* __restrict__ cwB,
                                            const float* __restrict__ cb,
                                            unsigned* sVvT, int b, int x, int l,
                                            int wv, int lane) {
    int l15 = lane & 15, l4 = lane >> 4;
    // G B-fragments (both n-tiles), raw g (specA carries the 1/65536).
    bf16x8_t Ghi[2], Glo[2];
#pragma unroll
    for (int n = 0; n < 2; ++n) {
        float gv[8];
        if (l4 < 3) {
            const float* gp = g + (size_t)(b * 32 + n * 16 + l15) * 6144
                            + x * 24 + 8 * l4;
            float4 a = *reinterpret_cast<const float4*>(gp);
            float4 c = *reinterpret_cast<const float4*>(gp + 4);
            gv[0] = a.x; gv[1] = a.y; gv[2] = a.z; gv[3] = a.w;
            gv[4] = c.x; gv[5] = c.y; gv[6] = c.z; gv[7] = c.w;
        } else {
#pragma unroll
            for (int j = 0; j < 8; ++j) gv[j] = 0.f;
        }
#pragma unroll
        for (int j = 0; j < 8; ++j) {
            float v = gv[j];
            unsigned u = __float_as_uint(v);
            Ghi[n][j] = (short)(u >> 16);
            float r = v - __uint_as_float(u & 0xffff0000u);
            Glo[n][j] = (short)(__float_as_uint(r) >> 16);
        }
    }
    bf16x8_t Whi[2], Wlo[2];
#pragma unroll
    for (int n = 0; n < 2; ++n) {
        Whi[n] = *reinterpret_cast<const bf16x8_t*>(cwB + ((l * 2 + n) * 64 + lane) * 4);
        Wlo[n] = *reinterpret_cast<const bf16x8_t*>(cwB + 2048 + ((l * 2 + n) * 64 + lane) * 4);
    }
    float cbb[2] = {cb[l * 32 + l15], cb[l * 32 + 16 + l15]};
#pragma unroll
    for (int mtl = 0; mtl < 4; ++mtl) {
        int mtg = wv * 4 + mtl;
        bf16x8_t C2hi = *reinterpret_cast<const bf16x8_t*>(specA + (mtg * 64 + lane) * 4);
        bf16x8_t C2lo = *reinterpret_cast<const bf16x8_t*>(specA + 4096 + (mtg * 64 + lane) * 4);
        bf16x8_t Hhi, Hlo;
        {
            const float* hp = h + (size_t)(b * 32) * 65536 + x * 256 + mtg * 16 + l15;
#pragma unroll
            for (int j = 0; j < 8; ++j) {
                float v = hp[(size_t)(8 * l4 + j) * 65536];
                unsigned u = __float_as_uint(v);
                Hhi[j] = (short)(u >> 16);
                float r = v - __uint_as_float(u & 0xffff0000u);
                Hlo[j] = (short)(__float_as_uint(r) >> 16);
            }
        }
#pragma unroll
        for (int n = 0; n < 2; ++n) {
            f32x4_t acc = {0.f, 0.f, 0.f, 0.f};
            acc = __builtin_amdgcn_mfma_f32_16x16x32_bf16(C2hi, Ghi[n], acc, 0, 0, 0);
            acc = __builtin_amdgcn_mfma_f32_16x16x32_bf16(C2lo, Ghi[n], acc, 0, 0, 0);
            acc = __builtin_amdgcn_mfma_f32_16x16x32_bf16(C2hi, Glo[n], acc, 0, 0, 0);
            acc = __builtin_amdgcn_mfma_f32_16x16x32_bf16(Hhi, Whi[n], acc, 0, 0, 0);
            acc = __builtin_amdgcn_mfma_f32_16x16x32_bf16(Hlo, Whi[n], acc, 0, 0, 0);
            acc = __builtin_amdgcn_mfma_f32_16x16x32_bf16(Hhi, Wlo[n], acc, 0, 0, 0);
            uint4 pu;
            {
                float v0 = acc[0] + cbb[n], v1 = acc[1] + cbb[n];
                float v2 = acc[2] + cbb[n], v3 = acc[3] + cbb[n];
                if (ACT) { v0 = fgelu(v0); v1 = fgelu(v1); v2 = fgelu(v2); v3 = fgelu(v3); }
                pu.x = packsplit(v0); pu.y = packsplit(v1);
                pu.z = packsplit(v2); pu.w = packsplit(v3);
            }
            *reinterpret_cast<uint4*>(&sVvT[(n * 16 + l15) * 260 + mtg * 16 + l4 * 4]) = pu;
        }
    }
}

// Layers 0..2: MFMA spec+bypass+gelu, h write, MFMA ky-DFT tail.
__global__ __launch_bounds__(256) void k_dinvf(float* __restrict__ h,
                                               const float* __restrict__ g,
                                               const unsigned* __restrict__ specA,
                                               const unsigned* __restrict__ tailA,
                                               const unsigned* __restrict__ cwB,
                                               const float* __restrict__ cb,
                                               float* __restrict__ tmp, int l) {
    __shared__ unsigned sVvT[32 * 260];
    int b = blockIdx.x >> 8, x = blockIdx.x & 255;
    int tid = threadIdx.x, wv = tid >> 6, lane = tid & 63;
    int l15 = lane & 15, l4 = lane >> 4;
    dinv_phaseA<1>(h, g, specA, cwB, cb, sVvT, b, x, l, wv, lane);
    __syncthreads();
    // h write (coalesced): reconstruct fp32 = bf(hi) + bf(lo).
    {
        size_t hb = (size_t)(b * 32) * 65536 + x * 256 + tid;
#pragma unroll 8
        for (int o = 0; o < 32; ++o) {
            unsigned u = sVvT[o * 260 + tid];
            h[hb + (size_t)o * 65536] =
                __uint_as_float(u & 0xffff0000u) + __uint_as_float(u << 16);
        }
    }
    // tail GEMM: wave quadrant (mtj, nq).
    {
        int mtj = wv >> 1, nq = wv & 1;
        f32x4_t acc = {0.f, 0.f, 0.f, 0.f};
        for (int kk = 0; kk < 8; ++kk) {
            bf16x8_t Ehi = *reinterpret_cast<const bf16x8_t*>(
                tailA + ((kk * 2 + mtj) * 64 + lane) * 4);
            bf16x8_t Elo = *reinterpret_cast<const bf16x8_t*>(
                tailA + 4096 + ((kk * 2 + mtj) * 64 + lane) * 4);
            int base = (nq * 16 + l15) * 260 + kk * 32 + 8 * l4;
            uint4 va = *reinterpret_cast<const uint4*>(&sVvT[base]);
            uint4 vb = *reinterpret_cast<const uint4*>(&sVvT[base + 4]);
            bf16x8_t Vhi, Vlo;
            Vhi[0] = (short)(va.x >> 16); Vlo[0] = (short)(va.x & 0xffffu);
            Vhi[1] = (short)(va.y >> 16); Vlo[1] = (short)(va.y & 0xffffu);
            Vhi[2] = (short)(va.z >> 16); Vlo[2] = (short)(va.z & 0xffffu);
            Vhi[3] = (short)(va.w >> 16); Vlo[3] = (short)(va.w & 0xffffu);
            Vhi[4] = (short)(vb.x >> 16); Vlo[4] = (short)(vb.x & 0xffffu);
            Vhi[5] = (short)(vb.y >> 16); Vlo[5] = (short)(vb.y & 0xffffu);
            Vhi[6] = (short)(vb.z >> 16); Vlo[6] = (short)(vb.z & 0xffffu);
            Vhi[7] = (short)(vb.w >> 16); Vlo[7] = (short)(vb.w & 0xffffu);
            acc = __builtin_amdgcn_mfma_f32_16x16x32_bf16(Ehi, Vhi, acc, 0, 0, 0);
            acc = __builtin_amdgcn_mfma_f32_16x16x32_bf16(Ehi, Vlo, acc, 0, 0, 0);
            acc = __builtin_amdgcn_mfma_f32_16x16x32_bf16(Elo, Vhi, acc, 0, 0, 0);
        }
        int j0 = mtj * 16 + l4 * 4;
        if (j0 < 24) {
            float4 st = {acc[0], acc[1], acc[2], acc[3]};
            *reinterpret_cast<float4*>(
                tmp + (size_t)(b * 32 + nq * 16 + l15) * 6144 + x * 24 + j0) = st;
        }
    }
}

// Layer 3 (no gelu) + final MLP; phase B processed one mt-tile at a time
// (rolled loops: live set ~40 VGPR, body I-cache resident).
__global__ __launch_bounds__(256) void k_dinvmlp(const float* __restrict__ h,
                                                 const float* __restrict__ g,
                                                 const unsigned* __restrict__ specA,
                                                 const unsigned* __restrict__ cwB,
                                                 const float* __restrict__ cb,
                                                 const unsigned* __restrict__ wB,
                                                 const float* __restrict__ b0,
                                                 const float* __restrict__ w1p,
                                                 const float* __restrict__ b1,
                                                 float* __restrict__ out) {
    __shared__ unsigned sVvT[32 * 260];
    __shared__ float sOut[256 * 5];
    int b = blockIdx.x >> 8, x = blockIdx.x & 255;
    int tid = threadIdx.x, wv = tid >> 6, lane = tid & 63;
    int l15 = lane & 15, l4 = lane >> 4;
    dinv_phaseA<0>(h, g, specA, cwB, cb, sVvT, b, x, 3, wv, lane);
    __syncthreads();
    // Phase B: per mt-tile: A-frags, n-loop (3 MFMA + gelu + W1 fma), reduce.
#pragma unroll 1
    for (int mt = 0; mt < 4; ++mt) {
        bf16x8_t Ahi, Alo;
        int rowY = (wv << 6) + (mt << 4) + l15;
#pragma unroll
        for (int j = 0; j < 8; ++j) {
            unsigned u = sVvT[(8 * l4 + j) * 260 + rowY];
            Ahi[j] = (short)(u >> 16);
            Alo[j] = (short)(u & 0xffffu);
        }
        float ap0[4], ap1[4], ap2[4];
#pragma unroll
        for (int r = 0; r < 4; ++r) { ap0[r] = 0.f; ap1[r] = 0.f; ap2[r] = 0.f; }
#pragma unroll 1
        for (int n = 0; n < 8; ++n) {
            bf16x8_t Bhi = *reinterpret_cast<const bf16x8_t*>(wB + (n * 64 + lane) * 4);
            bf16x8_t Blo = *reinterpret_cast<const bf16x8_t*>(wB + 2048 + (n * 64 + lane) * 4);
            int km = (n << 4) + l15;
            float b0v  = b0[km];
            float w1v0 = w1p[km], w1v1 = w1p[128 + km], w1v2 = w1p[256 + km];
            f32x4_t acc = {0.f, 0.f, 0.f, 0.f};
            acc = __builtin_amdgcn_mfma_f32_16x16x32_bf16(Ahi, Bhi, acc, 0, 0, 0);
            acc = __builtin_amdgcn_mfma_f32_16x16x32_bf16(Ahi, Blo, acc, 0, 0, 0);
            acc = __builtin_amdgcn_mfma_f32_16x16x32_bf16(Alo, Bhi, acc, 0, 0, 0);
#pragma unroll
            for (int r = 0; r < 4; ++r) {
                float tg = fgelu(acc[r] + b0v);
                ap0[r] = __builtin_fmaf(tg, w1v0, ap0[r]);
                ap1[r] = __builtin_fmaf(tg, w1v1, ap1[r]);
                ap2[r] = __builtin_fmaf(tg, w1v2, ap2[r]);
            }
        }
#pragma unroll
        for (int r = 0; r < 4; ++r) {
            float v0 = ap0[r], v1 = ap1[r], v2 = ap2[r];
            v0 += __shfl_xor(v0, 1); v1 += __shfl_xor(v1, 1); v2 += __shfl_xor(v2, 1);
            v0 += __shfl_xor(v0, 2); v1 += __shfl_xor(v1, 2); v2 += __shfl_xor(v2, 2);
            v0 += __shfl_xor(v0, 4); v1 += __shfl_xor(v1, 4); v2 += __shfl_xor(v2, 4);
            v0 += __shfl_xor(v0, 8); v1 += __shfl_xor(v1, 8); v2 += __shfl_xor(v2, 8);
            if (l15 == 0) {
                int row = (wv << 6) + (mt << 4) + (l4 << 2) + r;
                sOut[row * 5 + 0] = v0;
                sOut[row * 5 + 1] = v1;
                sOut[row * 5 + 2] = v2;
            }
        }
    }
    __syncthreads();
    float b1v0 = b1[0], b1v1 = b1[1], b1v2 = b1[2];
    out[(((size_t)b * 3 + 0) * 256 + x) * 256 + tid] = sOut[tid * 5 + 0] + b1v0;
    out[(((size_t)b * 3 + 1) * 256 + x) * 256 + tid] = sOut[tid * 5 + 1] + b1v1;
    out[(((size_t)b * 3 + 2) * 256 + x) * 256 + tid] = sOut[tid * 5 + 2] + b1v2;
}

extern "C" void kernel_launch(void* const* d_in, const int* in_sizes, int n_in,
                              void* d_out, int out_size, void* d_ws, size_t ws_size,
                              hipStream_t stream) {
    const float* xin  = (const float*)d_in[0];
    const float* pw   = (const float*)d_in[1];
    const float* pb   = (const float*)d_in[2];
    const float* sw1r = (const float*)d_in[3];
    const float* sw1i = (const float*)d_in[4];
    const float* sw2r = (const float*)d_in[5];
    const float* sw2i = (const float*)d_in[6];
    const float* cw   = (const float*)d_in[7];
    const float* cb   = (const float*)d_in[8];
    const float* w0   = (const float*)d_in[9];
    const float* b0   = (const float*)d_in[10];
    const float* w1   = (const float*)d_in[11];
    const float* b1   = (const float*)d_in[12];
    float* out = (float*)d_out;

    unsigned* specA = (unsigned*)d_ws;         // 8192 u32
    unsigned* tailA = specA + 8192;            // 8192
    unsigned* cwB   = tailA + 8192;            // 4096
    unsigned* wB    = cwB + 4096;              // 4096
    float* w1p = (float*)(wB + 4096);          // 384
    float* h   = w1p + 384;                    // 8388608
    float* tmp = h + 8388608;                  // 786432 (aliased with g)
    float* hfp = tmp + 786432;                 // 294912
    float* g   = tmp;                          // alias

    k_init<<<1, 256, 0, stream>>>(w0, b0, w1, cw, specA, tailA, cwB, wB, w1p);
    k_liftf<<<1024, 256, 0, stream>>>(xin, pw, pb, h, tmp);
    for (int l = 0; l < 4; ++l) {
        k_dftx<<<512, 320, 0, stream>>>(tmp, hfp);
        k_mixcinv<<<128, 320, 0, stream>>>(hfp, sw1r, sw1i, sw2r, sw2i, g, l);
        if (l < 3)
            k_dinvf<<<1024, 256, 0, stream>>>(h, g, specA, tailA, cwB, cb, tmp, l);
        else
            k_dinvmlp<<<1024, 256, 0, stream>>>(h, g, specA, cwB, cb, wB, b0, w1p,
                                                b1, out);
    }
}